// Round 13
// baseline (21.361 us; speedup 1.0000x reference)
//
#include <hip/hip_runtime.h>

// FocalLoss (sigmoid focal, mean reduction) — R13.
//   cls_score: [N=4, C=19, H=512, W=512] float32  (76 MiB, streamed once)
//   label:     [N=4, H=512, W=512] int32          (4 MiB, re-read 19x, cache-hot)
//
// Ledger (measured):
//  - NEVER fuse the last-block tail (R2/R7/R9: regalloc collapse -> 100+ us).
//  - Work removal pays ~1:1 (trans -3us R8, LDS -0.8us R11); structure levers
//    (MLP R10, occupancy R12) are null -> VALU & memory run near-sum.
// R13 lever: halve VALU via packed f32 (v_pk_fma_f32 & co). Element-pair math
// as float2 ext_vectors: y = x*(1-2t); d = y+t; w = av*d*d;
// bce = max(y,0) + poly6(|x|).  ~17 VOP3P instrs/pair vs ~50 scalar.
// Only the int-compare selects (t, valid) remain scalar.

#define NC 19
#define IGNORE_INDEX 255
#define ALPHA 0.25f

typedef float f32x4 __attribute__((ext_vector_type(4)));
typedef float f32x2 __attribute__((ext_vector_type(2)));
typedef int   i32x4 __attribute__((ext_vector_type(4)));

constexpr int NBATCH = 4;
constexpr int HW = 512 * 512;                       // 2^18
constexpr int NQ = NBATCH * NC * (HW / 4);          // 4,980,736 float4-quads
constexpr int BLOCK = 256;
constexpr int QPT = 4;                              // quads per thread
constexpr int GRID = NQ / (BLOCK * QPT);            // 4864, exact
constexpr int TT = GRID * BLOCK;                    // 1,245,184 (stride)
constexpr int BLOCK2 = 1024;
constexpr float INV_TOTAL = 1.0f / (float)(NBATCH * NC * HW);

// Chebyshev-interpolant (7 nodes) of log1p(exp(-u)) on u in [0,6],
// monomials of x = u/3 - 1. Max err ~3.5e-4 (<< 5.5e-3 threshold).
constexpr float A0 =  0.0485865f;
constexpr float A1 = -0.1402039f;
constexpr float A2 =  0.2024491f;
constexpr float A3 = -0.2005852f;
constexpr float A4 =  0.1182934f;
constexpr float A5 = -0.0048016f;
constexpr float A6 = -0.0214538f;

template <int NWAVE>
__device__ __forceinline__ float block_reduce(float v, float* smem) {
    #pragma unroll
    for (int off = 32; off > 0; off >>= 1)
        v += __shfl_down(v, off, 64);
    const int lane = threadIdx.x & 63;
    const int wid  = threadIdx.x >> 6;
    if (lane == 0) smem[wid] = v;
    __syncthreads();
    float s = 0.0f;
    if (threadIdx.x == 0) {
        #pragma unroll
        for (int i = 0; i < NWAVE; ++i) s += smem[i];
    }
    return s;  // valid in thread 0 only
}

// One element-pair, fully packed-f32 except the int-compare mask generation.
__device__ __forceinline__ void pair_loss(const f32x2 xv, const int lb0,
                                          const int lb1, const int c,
                                          f32x2& acc) {
    // scalar mask gen (v_cmp + v_cndmask)
    const float tf0 = (lb0 == c) ? 1.0f : 0.0f;
    const float tf1 = (lb1 == c) ? 1.0f : 0.0f;
    const float av0 = ((lb0 >= 0) && (lb0 != IGNORE_INDEX)) ? ALPHA : 0.0f;
    const float av1 = ((lb1 >= 0) && (lb1 != IGNORE_INDEX)) ? ALPHA : 0.0f;
    const f32x2 tf = {tf0, tf1};
    const f32x2 av = {av0, av1};

    const f32x2 ZERO = {0.0f, 0.0f};
    const f32x2 SIX  = {6.0f, 6.0f};

    const f32x2 m2 = tf * -2.0f;                                  // pk_mul
    const f32x2 y  = __builtin_elementwise_fma(m2, xv, xv);       // x*(1-2t)
    const f32x2 d  = y + tf;                                      // t?1-x:x

    const f32x2 u  = __builtin_elementwise_min(
                         __builtin_elementwise_abs(xv), SIX);
    f32x2 xx = u * (1.0f / 3.0f);
    xx = xx - 1.0f;
    f32x2 sp = {A6, A6};
    const f32x2 C5 = {A5, A5}, C4 = {A4, A4}, C3 = {A3, A3},
                C2 = {A2, A2}, C1 = {A1, A1}, C0 = {A0, A0};
    sp = __builtin_elementwise_fma(sp, xx, C5);
    sp = __builtin_elementwise_fma(sp, xx, C4);
    sp = __builtin_elementwise_fma(sp, xx, C3);
    sp = __builtin_elementwise_fma(sp, xx, C2);
    sp = __builtin_elementwise_fma(sp, xx, C1);
    sp = __builtin_elementwise_fma(sp, xx, C0);

    const f32x2 bce = __builtin_elementwise_max(y, ZERO) + sp;
    const f32x2 w   = av * d * d;
    acc = __builtin_elementwise_fma(bce, w, acc);
}

__device__ __forceinline__ void quad_loss(const f32x4 v, const i32x4 l4,
                                          const int c, f32x2& acc) {
    const f32x2 lo = {v.x, v.y};
    const f32x2 hi = {v.z, v.w};
    pair_loss(lo, l4.x, l4.y, c, acc);
    pair_loss(hi, l4.z, l4.w, c, acc);
}

__global__ __launch_bounds__(BLOCK, 8) void focal_partial(
        const f32x4* __restrict__ x,
        const i32x4* __restrict__ lab4,
        float*       __restrict__ partial) {
    const int tid = blockIdx.x * BLOCK + threadIdx.x;

    // Per-quad class ids / label indices (q_k = tid + k*TT, exact tiling).
    int c_[QPT];
    int li_[QPT];
    #pragma unroll
    for (int k = 0; k < QPT; ++k) {
        const int      q     = tid + k * TT;
        const unsigned plane = (unsigned)q >> 16;
        const unsigned n     = plane / NC;          // magic-mul div
        c_[k]  = (int)(plane - n * NC);
        li_[k] = (int)((n << 16) + (q & 65535));
    }

    // Issue all 8 loads back-to-back; pin live (R7/R9 serialization guard).
    f32x4 v0 = __builtin_nontemporal_load(x + tid + 0 * TT),
          v1 = __builtin_nontemporal_load(x + tid + 1 * TT),
          v2 = __builtin_nontemporal_load(x + tid + 2 * TT),
          v3 = __builtin_nontemporal_load(x + tid + 3 * TT);
    i32x4 l0 = lab4[li_[0]], l1 = lab4[li_[1]],
          l2 = lab4[li_[2]], l3 = lab4[li_[3]];
    asm volatile("" : "+v"(v0), "+v"(v1), "+v"(v2), "+v"(v3),
                      "+v"(l0), "+v"(l1), "+v"(l2), "+v"(l3));

    f32x2 acc2 = {0.0f, 0.0f};
    quad_loss(v0, l0, c_[0], acc2);
    quad_loss(v1, l1, c_[1], acc2);
    quad_loss(v2, l2, c_[2], acc2);
    quad_loss(v3, l3, c_[3], acc2);
    const float acc = acc2.x + acc2.y;

    __shared__ float smem[BLOCK / 64];
    const float s = block_reduce<BLOCK / 64>(acc, smem);
    if (threadIdx.x == 0) partial[blockIdx.x] = s;
}

__global__ __launch_bounds__(BLOCK2) void focal_finalize(
        const float* __restrict__ partial,
        float*       __restrict__ out) {
    float acc = 0.0f;
    for (int i = threadIdx.x; i < GRID; i += BLOCK2)
        acc += partial[i];
    __shared__ float smem[BLOCK2 / 64];
    const float s = block_reduce<BLOCK2 / 64>(acc, smem);
    if (threadIdx.x == 0) out[0] = s * INV_TOTAL;  // LOSS_WEIGHT == 1.0
}

extern "C" void kernel_launch(void* const* d_in, const int* in_sizes, int n_in,
                              void* d_out, int out_size, void* d_ws, size_t ws_size,
                              hipStream_t stream) {
    const f32x4* cls_score = (const f32x4*)d_in[0];
    const i32x4* lab4      = (const i32x4*)d_in[1];
    float* out     = (float*)d_out;
    float* partial = (float*)d_ws;   // GRID floats

    focal_partial<<<GRID, BLOCK, 0, stream>>>(cls_score, lab4, partial);
    focal_finalize<<<1, BLOCK2, 0, stream>>>(partial, out);
}